// Round 4
// baseline (370.003 us; speedup 1.0000x reference)
//
#include <hip/hip_runtime.h>
#include <hip/hip_bf16.h>
#include <cstdint>

// B=256, H=128, N=1000.
// logits[b,n] = sum_h v[h] * tanh( sum_{k<384} W[h,k]*X[b,k,n] + cterm[b,h] )
// out[b,n]    = softmax_n(logits[b,:])
// X = concat(adj, static, dyn); cterm = W[:,384:512] @ dec[b].
// Round 4: depth-3 rotating X prefetch (never drain vmcnt to 0) — R3 was
// latency-bound by its 1-deep issue/drain pattern (20% HBM, all pipes <30%).

#define BB 256
#define HH 128
#define NN 1000
#define K3 384
#define WROW 784                 // LDS bytes per Wh row: 384*2 + 16 pad (16B-aligned)
#define WLDS (HH * WROW)         // 100352
#define CT_OFF WLDS              // cterm row (128 f32)
#define VV_OFF (WLDS + 512)      // v vector (128 f32)
#define SMEM_ATTN (WLDS + 1024)  // 101376 B

typedef __attribute__((ext_vector_type(8))) short short8;
typedef __attribute__((ext_vector_type(4))) float f32x4;

__device__ __forceinline__ uint32_t pk_bf16_rn(float a, float b) {
    union { __hip_bfloat162 h2; uint32_t u; } cv;
    cv.h2 = __float22bfloat162_rn(make_float2(a, b));
    return cv.u;
}
__device__ __forceinline__ float fast_tanh(float x) {
    float e = __expf(2.0f * x);
    return 1.0f - 2.0f * __builtin_amdgcn_rcpf(e + 1.0f);
}

// ---------------- prep: W split (bf16 hi only) + cterm mini-GEMM ----------------
__global__ void prep_kernel(const float* __restrict__ W, const float* __restrict__ dec,
                            uint16_t* __restrict__ Whi, float* __restrict__ cterm) {
    extern __shared__ float ls[];
    const int tid = threadIdx.x;
    if (blockIdx.x < 48) {
        // W[:, :384] -> bf16 ; 12288 float4 chunks, coalesced
        int idx4 = blockIdx.x * 256 + tid;
        int h = idx4 / 96, k4 = idx4 - h * 96;
        float4 w = *(const float4*)(W + h * 512 + k4 * 4);
        uint2 o;
        o.x = pk_bf16_rn(w.x, w.y);
        o.y = pk_bf16_rn(w.z, w.w);
        *(uint2*)(Whi + h * K3 + k4 * 4) = o;
    } else {
        // cterm[b,h] = sum_k W[h,384+k]*dec[b,k]; 8 b per block, W4+dec in LDS
        float* w4 = ls;              // 128 x 129 (padded, conflict-free)
        float* dl = ls + 128 * 129;  // 8 x 128
        const int bb = (blockIdx.x - 48) * 8;
#pragma unroll
        for (int i = 0; i < 16; ++i) {
            int chunk = tid + i * 256;
            int h = chunk >> 5, kq = chunk & 31;
            float4 v = *(const float4*)(W + h * 512 + 384 + kq * 4);
            float* d = w4 + h * 129 + kq * 4;
            d[0] = v.x; d[1] = v.y; d[2] = v.z; d[3] = v.w;
        }
        {
            float4 dv = *(const float4*)(dec + bb * HH + tid * 4);
            float* d = dl + tid * 4;
            d[0] = dv.x; d[1] = dv.y; d[2] = dv.z; d[3] = dv.w;
        }
        __syncthreads();
#pragma unroll
        for (int r = 0; r < 4; ++r) {
            int o = tid + r * 256;
            int h = o & 127, bl_ = o >> 7;
            const float* wr = w4 + h * 129;
            const float* dr = dl + bl_ * 128;
            float s = 0.f;
#pragma unroll 8
            for (int k = 0; k < 128; ++k) s += wr[k] * dr[k];
            cterm[(bb + bl_) * HH + h] = s;
        }
    }
}

// ---------------- main: GEMM + tanh + v-dot -> logits ----------------
__launch_bounds__(1024, 4)
__global__ void attn_main(const float* __restrict__ adj, const float* __restrict__ sta,
                          const float* __restrict__ dyn,
                          const uint16_t* __restrict__ Whi,
                          const float* __restrict__ cterm, const float* __restrict__ vvec,
                          float* __restrict__ logits) {
    extern __shared__ char smem[];
    const int tid = threadIdx.x;
    const int b = blockIdx.x >> 2;
    const int tile = blockIdx.x & 3;

    // ---- stage Wh into LDS (padded rows): 128 rows x 768 B = 48 x 16B chunks/row ----
#pragma unroll
    for (int i = 0; i < 6; ++i) {
        int ch = tid + i * 1024;            // 6144 chunks of 16 B
        int h = ch / 48, j = ch - h * 48;
        *(uint4*)(smem + h * WROW + j * 16) = *(const uint4*)(Whi + h * K3 + j * 8);
    }
    if (tid < 32) {
        ((float4*)(smem + CT_OFF))[tid] = ((const float4*)(cterm + b * HH))[tid];
    } else if (tid < 64) {
        ((float4*)(smem + VV_OFF))[tid - 32] = ((const float4*)vvec)[tid - 32];
    }
    __syncthreads();

    const int wave = tid >> 6, lane = tid & 63;
    const int c = lane & 15, q = lane >> 4;
    const int n = tile * 256 + wave * 16 + c;
    const int ncl = (n < NN) ? n : NN - 1;
    const long bbase = (long)b * HH * NN;
    const float* A0 = adj + bbase;
    const float* A1 = sta + bbase;
    const float* A2 = dyn + bbase;

    f32x4 acc[8];
#pragma unroll
    for (int m = 0; m < 8; ++m) acc[m] = (f32x4){0.f, 0.f, 0.f, 0.f};

    union fu { uint32_t u[4]; short8 s; };

    // depth-3 rotating prefetch: batches it, it+1, it+2 always in flight
#define LOAD_BATCH(t, dst)                                                    \
    do {                                                                      \
        const int tt_ = (t) >> 2, cc_ = (t) & 3;                              \
        const float* bp_ = (tt_ == 0) ? A0 : ((tt_ == 1) ? A1 : A2);          \
        const float* p_ = bp_ + (cc_ * 32 + 8 * q) * NN + ncl;                \
        _Pragma("unroll") for (int j_ = 0; j_ < 8; ++j_) (dst)[j_] = p_[j_ * NN]; \
    } while (0)

    float xs[3][8];
    LOAD_BATCH(0, xs[0]);
    LOAD_BATCH(1, xs[1]);
    LOAD_BATCH(2, xs[2]);

#pragma unroll
    for (int it = 0; it < 12; ++it) {
        const int slot = it % 3;
        float xc[8];
#pragma unroll
        for (int j = 0; j < 8; ++j) xc[j] = xs[slot][j];

        // hi/lo split into B-fragments (waits only on the oldest batch)
        fu bh, bl;
#pragma unroll
        for (int j = 0; j < 4; ++j) {
            float a = xc[2 * j], d = xc[2 * j + 1];
            uint32_t u = pk_bf16_rn(a, d);
            bh.u[j] = u;
            float la = a - __uint_as_float(u << 16);
            float lb = d - __uint_as_float(u & 0xFFFF0000u);
            bl.u[j] = pk_bf16_rn(la, lb);
        }

        // refill this slot 3 iterations ahead
        if (it + 3 < 12) LOAD_BATCH(it + 3, xs[slot]);

        // byte offset of this 32-k chunk inside a Wh LDS row
        const int rowoff = (it >> 2) * 256 + (it & 3) * 64 + q * 16;
#pragma unroll
        for (int m = 0; m < 8; ++m) {
            const short8 av = *(const short8*)(smem + (m * 16 + c) * WROW + rowoff);
            acc[m] = __builtin_amdgcn_mfma_f32_16x16x32_bf16(av, bh.s, acc[m], 0, 0, 0);
            acc[m] = __builtin_amdgcn_mfma_f32_16x16x32_bf16(av, bl.s, acc[m], 0, 0, 0);
        }
    }
#undef LOAD_BATCH

    // epilogue: C layout col=lane&15, row=q*4+r ; h = m*16 + q*4 + r
    const float* ct = (const float*)(smem + CT_OFF);
    const float* vv = (const float*)(smem + VV_OFF);
    float s = 0.0f;
#pragma unroll
    for (int m = 0; m < 8; ++m) {
#pragma unroll
        for (int r = 0; r < 4; ++r) {
            const int h = m * 16 + q * 4 + r;
            s += vv[h] * fast_tanh(acc[m][r] + ct[h]);
        }
    }
    s += __shfl_xor(s, 16, 64);
    s += __shfl_xor(s, 32, 64);
    if (lane < 16 && n < NN) logits[b * NN + n] = s;
}

// ---------------- softmax over n, in place on d_out ----------------
__global__ void softmax_kernel(float* __restrict__ out) {
    const int b = blockIdx.x;
    const int tid = threadIdx.x;
    float* row = out + b * NN;

    float vals[4];
#pragma unroll
    for (int i = 0; i < 4; ++i) {
        int j = tid + i * 256;
        vals[i] = (j < NN) ? row[j] : -1e30f;
    }
    float mx = fmaxf(fmaxf(vals[0], vals[1]), fmaxf(vals[2], vals[3]));
#pragma unroll
    for (int off = 1; off < 64; off <<= 1) mx = fmaxf(mx, __shfl_xor(mx, off, 64));
    __shared__ float smax[4];
    if ((tid & 63) == 0) smax[tid >> 6] = mx;
    __syncthreads();
    mx = fmaxf(fmaxf(smax[0], smax[1]), fmaxf(smax[2], smax[3]));

    float e[4];
    float s = 0.0f;
#pragma unroll
    for (int i = 0; i < 4; ++i) {
        int j = tid + i * 256;
        e[i] = (j < NN) ? __expf(vals[i] - mx) : 0.0f;
        s += e[i];
    }
#pragma unroll
    for (int off = 1; off < 64; off <<= 1) s += __shfl_xor(s, off, 64);
    __shared__ float ssum[4];
    if ((tid & 63) == 0) ssum[tid >> 6] = s;
    __syncthreads();
    s = ssum[0] + ssum[1] + ssum[2] + ssum[3];
    float inv = 1.0f / s;
#pragma unroll
    for (int i = 0; i < 4; ++i) {
        int j = tid + i * 256;
        if (j < NN) row[j] = e[i] * inv;
    }
}

extern "C" void kernel_launch(void* const* d_in, const int* in_sizes, int n_in,
                              void* d_out, int out_size, void* d_ws, size_t ws_size,
                              hipStream_t stream) {
    const float* adj = (const float*)d_in[0];
    const float* sta = (const float*)d_in[1];
    const float* dyn = (const float*)d_in[2];
    const float* dec = (const float*)d_in[3];
    const float* v   = (const float*)d_in[4];
    const float* W   = (const float*)d_in[5];

    uint16_t* Whi = (uint16_t*)d_ws;                 // 128*384*2 = 98304 B
    float* cterm  = (float*)(Whi + HH * K3);         // 256*128*4 = 131072 B
    float* logits = (float*)d_out;

    prep_kernel<<<80, 256, (128 * 129 + 1024) * 4, stream>>>(W, dec, Whi, cterm);
    attn_main<<<BB * 4, 1024, SMEM_ATTN, stream>>>(adj, sta, dyn, Whi, cterm, v, logits);
    softmax_kernel<<<BB, 256, 0, stream>>>(logits);
}